// Round 2
// baseline (990.606 us; speedup 1.0000x reference)
//
#include <hip/hip_runtime.h>
#include <stdint.h>
#include <math.h>

// MS_MSA: pos-emb (dw3x3 -> gelu -> dw3x3, residual), q/k/v depthwise 3x3 chains,
// channel attention via Gram matrix over pixels, folded epilogue GEMM.
// Inputs/outputs fp32 (per reference); intermediate images stored bf16.
//
// ws layout: S0,S1 = 2 x 64MiB bf16 image slots; smalls at ws+128MiB.
// d_out (128 MiB fp32) doubles as two bf16 scratch slots D0,D1 before the
// final GEMM overwrites it with the fp32 output.

using u16 = unsigned short;
using u32 = unsigned int;

typedef __bf16 bf16x8_t __attribute__((ext_vector_type(8)));
typedef float f32x4_t __attribute__((ext_vector_type(4)));

__device__ __forceinline__ float bf2f(u16 v) {
  u32 u = ((u32)v) << 16;
  return __builtin_bit_cast(float, u);
}
__device__ __forceinline__ u16 f2bf(float f) {
  u32 u = __builtin_bit_cast(u32, f);
  u32 r = u + 0x7fffu + ((u >> 16) & 1u);  // RNE (finite inputs)
  return (u16)(r >> 16);
}
__device__ __forceinline__ void unpack8(uint4 u, float f[8]) {
  f[0] = bf2f((u16)(u.x & 0xffffu)); f[1] = bf2f((u16)(u.x >> 16));
  f[2] = bf2f((u16)(u.y & 0xffffu)); f[3] = bf2f((u16)(u.y >> 16));
  f[4] = bf2f((u16)(u.z & 0xffffu)); f[5] = bf2f((u16)(u.z >> 16));
  f[6] = bf2f((u16)(u.w & 0xffffu)); f[7] = bf2f((u16)(u.w >> 16));
}

// Load 8 consecutive channel values starting at flat element index idx.
// F32=1: source is float[]; F32=0: source is bf16 (u16[]) intermediate.
template <int F32>
__device__ __forceinline__ void load8(const void* p, size_t idx, float f[8]) {
  if (F32) {
    const float4* q = reinterpret_cast<const float4*>((const float*)p + idx);
    const float4 a = q[0];
    const float4 b = q[1];
    f[0] = a.x; f[1] = a.y; f[2] = a.z; f[3] = a.w;
    f[4] = b.x; f[5] = b.y; f[6] = b.z; f[7] = b.w;
  } else {
    const uint4 u = *reinterpret_cast<const uint4*>((const u16*)p + idx);
    unpack8(u, f);
  }
}

// Depthwise 3x3 (cross-correlation, SAME zero pad), NHWC [px][256].
// IN_F32: input dtype. Output always bf16.
// WMODE: 0 = per-channel weights [(c,9)], 1 = per-head weights [(h,9)], h = c/32
// POST:  0 = none, 1 = exact gelu, 2 = add fp32 addsrc (residual)
// RED:   0 = none, 1 = sum of squares of ROUNDED value -> red[b*256+c],
//        2 = sum of ROUNDED value -> red[b*256+c]
template <int IN_F32, int WMODE, int POST, int RED>
__global__ __launch_bounds__(256) void dw3x3_kernel(
    const void* __restrict__ in, u16* __restrict__ out,
    const float* __restrict__ wgt, const float* __restrict__ bias,
    const float* __restrict__ addsrc, float* __restrict__ red) {
  const int t = threadIdx.x;
  const int oct = t & 31;   // channel octet: c = oct*8 .. oct*8+7
  const int pxl = t >> 5;   // 8 pixel groups
  const int c0 = oct * 8;
  const int base = blockIdx.x * 64;  // 64 pixels per block

  float w[(WMODE == 0) ? 72 : 9];
  if (WMODE == 0) {
#pragma unroll
    for (int j = 0; j < 8; ++j)
#pragma unroll
      for (int k = 0; k < 9; ++k) w[j * 9 + k] = wgt[(c0 + j) * 9 + k];
  } else {
    const int h = oct >> 2;
#pragma unroll
    for (int k = 0; k < 9; ++k) w[k] = wgt[h * 9 + k];
  }
  float bi[8];
#pragma unroll
  for (int j = 0; j < 8; ++j) bi[j] = 0.f;
  if (bias != nullptr) {
#pragma unroll
    for (int j = 0; j < 8; ++j) bi[j] = bias[c0 + j];
  }
  float racc[8];
#pragma unroll
  for (int j = 0; j < 8; ++j) racc[j] = 0.f;

  for (int i = 0; i < 8; ++i) {
    const int px = base + i * 8 + pxl;  // global pixel (b*65536 + y*256 + x)
    const int y = (px >> 8) & 255;
    const int x = px & 255;
    float a[8];
#pragma unroll
    for (int j = 0; j < 8; ++j) a[j] = bi[j];
#pragma unroll
    for (int ky = 0; ky < 3; ++ky) {
      const int yy = y + ky - 1;
      if (yy >= 0 && yy <= 255) {
#pragma unroll
        for (int kx = 0; kx < 3; ++kx) {
          const int xx = x + kx - 1;
          if (xx >= 0 && xx <= 255) {
            float f[8];
            load8<IN_F32>(in, (size_t)(px + (ky - 1) * 256 + (kx - 1)) * 256 + c0, f);
#pragma unroll
            for (int j = 0; j < 8; ++j) {
              const float wv = (WMODE == 0) ? w[j * 9 + ky * 3 + kx] : w[ky * 3 + kx];
              a[j] = fmaf(wv, f[j], a[j]);
            }
          }
        }
      }
    }
    if (POST == 1) {
#pragma unroll
      for (int j = 0; j < 8; ++j)
        a[j] = 0.5f * a[j] * (1.0f + erff(a[j] * 0.70710678118654752f));
    }
    if (POST == 2) {
      const float4* q = reinterpret_cast<const float4*>(addsrc + (size_t)px * 256 + c0);
      const float4 r0 = q[0];
      const float4 r1 = q[1];
      a[0] += r0.x; a[1] += r0.y; a[2] += r0.z; a[3] += r0.w;
      a[4] += r1.x; a[5] += r1.y; a[6] += r1.z; a[7] += r1.w;
    }
    u16 o[8];
    float rv[8];
#pragma unroll
    for (int j = 0; j < 8; ++j) {
      o[j] = f2bf(a[j]);
      rv[j] = bf2f(o[j]);
    }
    if (RED == 1) {
#pragma unroll
      for (int j = 0; j < 8; ++j) racc[j] = fmaf(rv[j], rv[j], racc[j]);
    }
    if (RED == 2) {
#pragma unroll
      for (int j = 0; j < 8; ++j) racc[j] += rv[j];
    }
    uint4 ov;
    ov.x = (u32)o[0] | ((u32)o[1] << 16);
    ov.y = (u32)o[2] | ((u32)o[3] << 16);
    ov.z = (u32)o[4] | ((u32)o[5] << 16);
    ov.w = (u32)o[6] | ((u32)o[7] << 16);
    *reinterpret_cast<uint4*>(out + (size_t)px * 256 + c0) = ov;
  }

  if (RED != 0) {
    __shared__ float rbuf[256];
    rbuf[t] = 0.f;
    __syncthreads();
#pragma unroll
    for (int j = 0; j < 8; ++j) atomicAdd(&rbuf[c0 + j], racc[j]);
    __syncthreads();
    const int b = base >> 16;
    atomicAdd(&red[b * 256 + t], rbuf[t]);
  }
}

// Computes k3 = dw3x3(k2, kw3[h]) for one (b, h, image row y), stages k3 and the
// (already materialized) q3 row into LDS as [d][px], then accumulates the raw Gram
// G[d][e] += sum_px k3[d,px]*q3[e,px] via mfma_f32_16x16x32_bf16, plus sum(k3^2).
__global__ __launch_bounds__(256) void kgram_kernel(
    const u16* __restrict__ k2, const u16* __restrict__ q3,
    const float* __restrict__ kw3, float* __restrict__ G, float* __restrict__ sqk) {
  const int bid = blockIdx.x;
  const int y = bid & 255;
  const int h = (bid >> 8) & 7;
  const int b = bid >> 11;
  const int t = threadIdx.x;
  const int oct = t & 3;   // d = oct*8 .. oct*8+7
  const int xl = t >> 2;   // 64 x-positions per pass

  __shared__ __align__(16) u16 k3s[32][264];  // [d][x], pad 8 to break conflicts
  __shared__ __align__(16) u16 q3s[32][264];  // [e][x]
  __shared__ float sk[32];
  if (t < 32) sk[t] = 0.f;
  __syncthreads();

  float w9[9];
#pragma unroll
  for (int k = 0; k < 9; ++k) w9[k] = kw3[h * 9 + k];
  const int c0 = h * 32 + oct * 8;
  const size_t rowpix = (size_t)(b * 256 + y) * 256;

  float ska[8];
#pragma unroll
  for (int j = 0; j < 8; ++j) ska[j] = 0.f;

  for (int i = 0; i < 4; ++i) {
    const int x = i * 64 + xl;
    float a[8];
#pragma unroll
    for (int j = 0; j < 8; ++j) a[j] = 0.f;
#pragma unroll
    for (int ky = 0; ky < 3; ++ky) {
      const int yy = y + ky - 1;
      if (yy >= 0 && yy <= 255) {
#pragma unroll
        for (int kx = 0; kx < 3; ++kx) {
          const int xx = x + kx - 1;
          if (xx >= 0 && xx <= 255) {
            const uint4 u = *reinterpret_cast<const uint4*>(
                k2 + ((size_t)(b * 256 + yy) * 256 + xx) * 256 + c0);
            float f[8];
            unpack8(u, f);
#pragma unroll
            for (int j = 0; j < 8; ++j) a[j] = fmaf(w9[ky * 3 + kx], f[j], a[j]);
          }
        }
      }
    }
#pragma unroll
    for (int j = 0; j < 8; ++j) {
      const u16 kb16 = f2bf(a[j]);
      const float kv = bf2f(kb16);
      k3s[oct * 8 + j][x] = kb16;
      ska[j] = fmaf(kv, kv, ska[j]);
    }
    const uint4 uq = *reinterpret_cast<const uint4*>(q3 + (rowpix + x) * 256 + c0);
    q3s[oct * 8 + 0][x] = (u16)(uq.x & 0xffffu);
    q3s[oct * 8 + 1][x] = (u16)(uq.x >> 16);
    q3s[oct * 8 + 2][x] = (u16)(uq.y & 0xffffu);
    q3s[oct * 8 + 3][x] = (u16)(uq.y >> 16);
    q3s[oct * 8 + 4][x] = (u16)(uq.z & 0xffffu);
    q3s[oct * 8 + 5][x] = (u16)(uq.z >> 16);
    q3s[oct * 8 + 6][x] = (u16)(uq.w & 0xffffu);
    q3s[oct * 8 + 7][x] = (u16)(uq.w >> 16);
  }
#pragma unroll
  for (int j = 0; j < 8; ++j) atomicAdd(&sk[oct * 8 + j], ska[j]);
  __syncthreads();
  if (t < 32) atomicAdd(&sqk[b * 256 + h * 32 + t], sk[t]);

  // Gram: wave w handles 16x16 quadrant (d0, e0). A[m][k]=k3[d0+m][px], B[k][n]=q3[e0+n][px]
  const int wave = t >> 6;
  const int lane = t & 63;
  const int quad = lane >> 4;
  const int l15 = lane & 15;
  const int d0 = (wave & 1) * 16;
  const int e0 = (wave >> 1) * 16;
  f32x4_t acc = {0.f, 0.f, 0.f, 0.f};
#pragma unroll
  for (int kb = 0; kb < 8; ++kb) {
    const bf16x8_t av =
        *reinterpret_cast<const bf16x8_t*>(&k3s[d0 + l15][kb * 32 + quad * 8]);
    const bf16x8_t bv =
        *reinterpret_cast<const bf16x8_t*>(&q3s[e0 + l15][kb * 32 + quad * 8]);
    acc = __builtin_amdgcn_mfma_f32_16x16x32_bf16(av, bv, acc, 0, 0, 0);
  }
  float* Gp = G + (size_t)((b * 8 + h) * 32) * 32;
#pragma unroll
  for (int r = 0; r < 4; ++r)
    atomicAdd(&Gp[(d0 + quad * 4 + r) * 32 + e0 + l15], acc[r]);
}

// Per-batch attention finalize: normalize Gram, conv1d(vmean) diagonal, softmax.
// grid(2), block(256): t = h*32 + d, computes attn[b,h,d,0..31].
__global__ __launch_bounds__(256) void attn_kernel(
    const float* __restrict__ G, const float* __restrict__ sqq,
    const float* __restrict__ sqk, const float* __restrict__ vsum,
    const float* __restrict__ cw, const float* __restrict__ cb,
    const float* __restrict__ rs1, const float* __restrict__ rs2,
    float* __restrict__ attn) {
  const int b = blockIdx.x;
  const int t = threadIdx.x;
  const int h = t >> 5;
  const int d = t & 31;
  __shared__ float vm[8][34];  // padded: vm[i][1+dd]
  __shared__ float nq[256];
  vm[h][d + 1] = vsum[b * 256 + t] * (1.0f / 65536.0f);
  if (t < 8) { vm[t][0] = 0.f; vm[t][33] = 0.f; }
  nq[t] = fmaxf(sqrtf(sqq[b * 256 + t]), 1e-12f);
  __syncthreads();

  // conv1d over dim_head, channels = heads, SAME pad, cross-correlation
  float av = cb[h];
#pragma unroll
  for (int i = 0; i < 8; ++i)
#pragma unroll
    for (int tau = 0; tau < 3; ++tau)
      av = fmaf(cw[h * 24 + i * 3 + tau], vm[i][d + tau], av);

  const float nk = fmaxf(sqrtf(sqk[b * 256 + t]), 1e-12f);
  const float rsc = rs1[h];
  const float rsc2 = rs2[h];
  const float* Gp = G + (size_t)((b * 8 + h) * 32 + d) * 32;
  float L[32];
#pragma unroll
  for (int e = 0; e < 32; ++e) {
    float l = Gp[e] * rsc / (nk * nq[h * 32 + e]);
    if (e == d) l += av * rsc2;
    L[e] = l;
  }
  float mx = L[0];
#pragma unroll
  for (int e = 1; e < 32; ++e) mx = fmaxf(mx, L[e]);
  float s = 0.f;
#pragma unroll
  for (int e = 0; e < 32; ++e) {
    L[e] = expf(L[e] - mx);
    s += L[e];
  }
  const float inv = 1.0f / s;
  float* Ap = attn + (size_t)((b * 8 + h) * 32 + d) * 32;
#pragma unroll
  for (int e = 0; e < 32; ++e) Ap[e] = L[e] * inv;
}

// M_b[c'][h*32+e] = sum_d proj_w[c'][h*32+d] * attn[b,h,d,e]  (bf16 output)
// grid(16) = (b,h), block(256): t = c'.
__global__ __launch_bounds__(256) void mbuild_kernel(
    const float* __restrict__ attn, const float* __restrict__ pw,
    u16* __restrict__ M) {
  const int bid = blockIdx.x;
  const int b = bid >> 3;
  const int h = bid & 7;
  const int t = threadIdx.x;
  __shared__ float at[32][33];
#pragma unroll
  for (int i = 0; i < 4; ++i) {
    const int idx = t * 4 + i;
    at[idx >> 5][idx & 31] = attn[(size_t)(b * 8 + h) * 1024 + idx];
  }
  __syncthreads();
  float pwf[32];
#pragma unroll
  for (int dd = 0; dd < 32; ++dd) pwf[dd] = pw[(size_t)t * 256 + h * 32 + dd];
  u16* Mp = M + (size_t)b * 65536 + (size_t)t * 256 + h * 32;
#pragma unroll
  for (int e = 0; e < 32; ++e) {
    float s = 0.f;
#pragma unroll
    for (int dd = 0; dd < 32; ++dd) s = fmaf(pwf[dd], at[dd][e], s);
    Mp[e] = f2bf(s);
  }
}

// out[m][c'] = sum_k v3[m][k] * M_b[c'][k] + proj_b[c'].  128x64 tile, BK=64.
// Output fp32.
__global__ __launch_bounds__(256) void gemm_kernel(
    const u16* __restrict__ V, const u16* __restrict__ Mm,
    const float* __restrict__ pb, float* __restrict__ out) {
  const int m0 = blockIdx.x * 128;
  const int n0 = blockIdx.y * 64;
  const int b = m0 >> 16;
  const u16* Mb = Mm + (size_t)b * 65536;

  __shared__ __align__(16) u16 As[128][72];
  __shared__ __align__(16) u16 Bs[64][72];

  const int t = threadIdx.x;
  const int wave = t >> 6;
  const int lane = t & 63;
  const int quad = lane >> 4;
  const int l15 = lane & 15;

  f32x4_t acc[2][4];
#pragma unroll
  for (int mt = 0; mt < 2; ++mt)
#pragma unroll
    for (int nt = 0; nt < 4; ++nt) acc[mt][nt] = {0.f, 0.f, 0.f, 0.f};

  for (int k0 = 0; k0 < 256; k0 += 64) {
#pragma unroll
    for (int i = 0; i < 4; ++i) {
      const int id = t + 256 * i;
      const int row = id >> 3;
      const int c8 = id & 7;
      *reinterpret_cast<uint4*>(&As[row][c8 * 8]) = *reinterpret_cast<const uint4*>(
          &V[(size_t)(m0 + row) * 256 + k0 + c8 * 8]);
    }
#pragma unroll
    for (int i = 0; i < 2; ++i) {
      const int id = t + 256 * i;
      const int row = id >> 3;
      const int c8 = id & 7;
      *reinterpret_cast<uint4*>(&Bs[row][c8 * 8]) = *reinterpret_cast<const uint4*>(
          &Mb[(size_t)(n0 + row) * 256 + k0 + c8 * 8]);
    }
    __syncthreads();
#pragma unroll
    for (int ks = 0; ks < 2; ++ks) {
      bf16x8_t af[2], bfv[4];
#pragma unroll
      for (int mt = 0; mt < 2; ++mt)
        af[mt] = *reinterpret_cast<const bf16x8_t*>(
            &As[wave * 32 + mt * 16 + l15][ks * 32 + quad * 8]);
#pragma unroll
      for (int nt = 0; nt < 4; ++nt)
        bfv[nt] = *reinterpret_cast<const bf16x8_t*>(
            &Bs[nt * 16 + l15][ks * 32 + quad * 8]);
#pragma unroll
      for (int mt = 0; mt < 2; ++mt)
#pragma unroll
        for (int nt = 0; nt < 4; ++nt)
          acc[mt][nt] =
              __builtin_amdgcn_mfma_f32_16x16x32_bf16(af[mt], bfv[nt], acc[mt][nt], 0, 0, 0);
    }
    __syncthreads();
  }

#pragma unroll
  for (int nt = 0; nt < 4; ++nt) {
    const int col = n0 + nt * 16 + l15;
    const float pbf = pb[col];
#pragma unroll
    for (int mt = 0; mt < 2; ++mt) {
#pragma unroll
      for (int r = 0; r < 4; ++r) {
        const int m = m0 + wave * 32 + mt * 16 + quad * 4 + r;
        out[(size_t)m * 256 + col] = acc[mt][nt][r] + pbf;
      }
    }
  }
}

extern "C" void kernel_launch(void* const* d_in, const int* in_sizes, int n_in,
                              void* d_out, int out_size, void* d_ws, size_t ws_size,
                              hipStream_t stream) {
  const float* x_in = (const float*)d_in[0];
  const float* qw1 = (const float*)d_in[1];
  const float* qw2 = (const float*)d_in[2];
  const float* qw3 = (const float*)d_in[3];
  const float* kw1 = (const float*)d_in[4];
  const float* kw2 = (const float*)d_in[5];
  const float* kw3 = (const float*)d_in[6];
  const float* vw1 = (const float*)d_in[7];
  const float* vw2 = (const float*)d_in[8];
  const float* vw3 = (const float*)d_in[9];
  const float* posw1 = (const float*)d_in[10];
  const float* posb1 = (const float*)d_in[11];
  const float* posw2 = (const float*)d_in[12];
  const float* posb2 = (const float*)d_in[13];
  const float* cw = (const float*)d_in[14];
  const float* cb = (const float*)d_in[15];
  const float* rs1 = (const float*)d_in[16];
  const float* rs2 = (const float*)d_in[17];
  const float* pw = (const float*)d_in[18];
  const float* pb = (const float*)d_in[19];

  char* ws = (char*)d_ws;
  const size_t SLOT = 67108864;  // one (2,256,256,256) bf16 image
  u16* S0 = (u16*)(ws);
  u16* S1 = (u16*)(ws + SLOT);
  u16* D0 = (u16*)d_out;                 // first bf16 slot inside d_out
  u16* D1 = (u16*)d_out + 33554432;      // second bf16 slot inside d_out
  char* SM = ws + 2 * SLOT;
  float* G = (float*)(SM);              // 2*8*32*32 f32 = 65536 B
  float* sqq = (float*)(SM + 65536);    // 2*256 f32
  float* sqk = (float*)(SM + 67584);    // 2*256 f32
  float* vsum = (float*)(SM + 69632);   // 2*256 f32
  float* attn = (float*)(SM + 71680);   // 2*8*32*32 f32
  u16* Mm = (u16*)(SM + 137216);        // 2*256*256 bf16

  // zero the atomic accumulators (ws is re-poisoned before every launch)
  hipMemsetAsync(SM, 0, 71680, stream);

  // positional embedding: t1 = gelu(dw(x,pos_w1)+b1); x2 = x + dw(t1,pos_w2)+b2
  dw3x3_kernel<1, 0, 1, 0><<<2048, 256, 0, stream>>>(x_in, S0, posw1, posb1, nullptr, nullptr);
  dw3x3_kernel<0, 0, 2, 0><<<2048, 256, 0, stream>>>(S0, S1, posw2, posb2, x_in, nullptr);
  // q chain (stage 3 also reduces sum(q3^2)); q3 -> D1
  dw3x3_kernel<0, 1, 0, 0><<<2048, 256, 0, stream>>>(S1, D0, qw1, nullptr, nullptr, nullptr);
  dw3x3_kernel<0, 1, 0, 0><<<2048, 256, 0, stream>>>(D0, S0, qw2, nullptr, nullptr, nullptr);
  dw3x3_kernel<0, 1, 0, 1><<<2048, 256, 0, stream>>>(S0, D1, qw3, nullptr, nullptr, sqq);
  // k chain; stage 3 fused with Gram reduction against q3
  dw3x3_kernel<0, 1, 0, 0><<<2048, 256, 0, stream>>>(S1, S0, kw1, nullptr, nullptr, nullptr);
  dw3x3_kernel<0, 1, 0, 0><<<2048, 256, 0, stream>>>(S0, D0, kw2, nullptr, nullptr, nullptr);
  kgram_kernel<<<4096, 256, 0, stream>>>(D0, D1, kw3, G, sqk);
  // v chain (stage 3 reduces sum(v3)); v3 -> S1
  dw3x3_kernel<0, 1, 0, 0><<<2048, 256, 0, stream>>>(S1, S0, vw1, nullptr, nullptr, nullptr);
  dw3x3_kernel<0, 1, 0, 0><<<2048, 256, 0, stream>>>(S0, D0, vw2, nullptr, nullptr, nullptr);
  dw3x3_kernel<0, 1, 0, 2><<<2048, 256, 0, stream>>>(D0, S1, vw3, nullptr, nullptr, vsum);
  // finalize attention and fold with proj into per-batch M
  attn_kernel<<<2, 256, 0, stream>>>(G, sqq, sqk, vsum, cw, cb, rs1, rs2, attn);
  mbuild_kernel<<<16, 256, 0, stream>>>(attn, pw, Mm);
  // out = v3 @ M_b^T + proj_b (fp32 output overwrites D0/D1)
  gemm_kernel<<<dim3(1024, 4), 256, 0, stream>>>(S1, Mm, pb, (float*)d_out);
}

// Round 4
// 947.361 us; speedup vs baseline: 1.0456x; 1.0456x over previous
//
#include <hip/hip_runtime.h>
#include <stdint.h>
#include <math.h>

// MS_MSA fused pipeline:
//   posemb_kernel : x2 = x + dw2(gelu(dw1(x)+b1))+b2            (2-stage tile fusion)
//   chain3_kernel : 3 chained per-head dw3x3 (q and v chains)    (3-stage tile fusion)
//   kchain_gram   : 3-stage k chain fused with MFMA Gram vs q3  (k3 never hits HBM)
//   attn/mbuild   : softmax + fold proj_w*blockdiag(attn) -> M
//   gemm          : out = v3 @ M_b^T + proj_b  (bf16 MFMA, fp32 out)
// Inputs/outputs fp32; intermediate images bf16.
// BORDER SEMANTICS: each dwconv zero-pads its OWN input, so intermediate
// stage values outside the image must be forced to 0 (not conv-of-padded-x).
// ws: S0=x2, S1=v3 (2 x 64MiB) + smalls; q3 lives in d_out's first half (dead
// before the final GEMM overwrites d_out).

using u16 = unsigned short;
using u32 = unsigned int;

typedef __bf16 bf16x8_t __attribute__((ext_vector_type(8)));
typedef float f32x4_t __attribute__((ext_vector_type(4)));

__device__ __forceinline__ float bf2f(u16 v) {
  u32 u = ((u32)v) << 16;
  return __builtin_bit_cast(float, u);
}
__device__ __forceinline__ u16 f2bf(float f) {
  u32 u = __builtin_bit_cast(u32, f);
  u32 r = u + 0x7fffu + ((u >> 16) & 1u);  // RNE (finite inputs)
  return (u16)(r >> 16);
}
__device__ __forceinline__ void unpack8(uint4 u, float f[8]) {
  f[0] = bf2f((u16)(u.x & 0xffffu)); f[1] = bf2f((u16)(u.x >> 16));
  f[2] = bf2f((u16)(u.y & 0xffffu)); f[3] = bf2f((u16)(u.y >> 16));
  f[4] = bf2f((u16)(u.z & 0xffffu)); f[5] = bf2f((u16)(u.z >> 16));
  f[6] = bf2f((u16)(u.w & 0xffffu)); f[7] = bf2f((u16)(u.w >> 16));
}
__device__ __forceinline__ uint4 pack8(const u16 o[8]) {
  uint4 v;
  v.x = (u32)o[0] | ((u32)o[1] << 16);
  v.y = (u32)o[2] | ((u32)o[3] << 16);
  v.z = (u32)o[4] | ((u32)o[5] << 16);
  v.w = (u32)o[6] | ((u32)o[7] << 16);
  return v;
}

// ---------------------------------------------------------------------------
// posemb: 2-stage fused, per-channel weights, fp32 input, gelu, residual.
// Tile 16x8 out; input region 20x12 (off -2); s1 region 18x10 (off -1).
// grid (16, 32, 16): (tx, ty, b*8+cg)
__global__ __launch_bounds__(256) void posemb_kernel(
    const float* __restrict__ xin, u16* __restrict__ x2,
    const float* __restrict__ w1g, const float* __restrict__ b1g,
    const float* __restrict__ w2g, const float* __restrict__ b2g) {
  const int t = threadIdx.x;
  const int o = t & 3;
  const int bz = blockIdx.z;
  const int cg = bz & 7;
  const int b = bz >> 3;
  const int x0 = blockIdx.x * 16;
  const int y0 = blockIdx.y * 8;
  const int c0 = cg * 32 + o * 8;  // this thread's 8 channels

  __shared__ __align__(16) u16 Abuf[240 * 32];  // input 20x12 tile, bf16
  __shared__ __align__(16) u16 Bbuf[180 * 32];  // s1 18x10 tile, bf16

  // P0: load input region (zero outside image), round to bf16
  for (int i = t; i < 240 * 4; i += 256) {
    const int px = i >> 2, oo = i & 3;
    const int lx = px % 20, ly = px / 20;
    const int gx = x0 - 2 + lx, gy = y0 - 2 + ly;
    u16 ov[8];
    if (gx >= 0 && gx < 256 && gy >= 0 && gy < 256) {
      const float* p = xin + ((size_t)((b << 16) + (gy << 8) + gx)) * 256 + cg * 32 + oo * 8;
      const float4 r0 = *reinterpret_cast<const float4*>(p);
      const float4 r1 = *reinterpret_cast<const float4*>(p + 4);
      ov[0] = f2bf(r0.x); ov[1] = f2bf(r0.y); ov[2] = f2bf(r0.z); ov[3] = f2bf(r0.w);
      ov[4] = f2bf(r1.x); ov[5] = f2bf(r1.y); ov[6] = f2bf(r1.z); ov[7] = f2bf(r1.w);
    } else {
#pragma unroll
      for (int j = 0; j < 8; ++j) ov[j] = 0;
    }
    *reinterpret_cast<uint4*>(Abuf + px * 32 + oo * 8) = pack8(ov);
  }
  __syncthreads();

  // P1: s1 = gelu(dw1(x)+b1) over 18x10 — ZERO outside image (per-stage pad)
  {
    float w[72], bi[8];
#pragma unroll
    for (int j = 0; j < 8; ++j) {
#pragma unroll
      for (int k = 0; k < 9; ++k) w[j * 9 + k] = w1g[(c0 + j) * 9 + k];
      bi[j] = b1g[c0 + j];
    }
    for (int i = t; i < 180 * 4; i += 256) {
      const int px = i >> 2;
      const int sx = px % 18, sy = px / 18;
      const int gx = x0 - 1 + sx, gy = y0 - 1 + sy;
      const bool inb = (gx >= 0 && gx < 256 && gy >= 0 && gy < 256);
      float a[8];
#pragma unroll
      for (int j = 0; j < 8; ++j) a[j] = bi[j];
#pragma unroll
      for (int ky = 0; ky < 3; ++ky)
#pragma unroll
        for (int kx = 0; kx < 3; ++kx) {
          float f[8];
          unpack8(*reinterpret_cast<const uint4*>(
                      Abuf + ((sy + ky) * 20 + sx + kx) * 32 + o * 8), f);
#pragma unroll
          for (int j = 0; j < 8; ++j) a[j] = fmaf(w[j * 9 + ky * 3 + kx], f[j], a[j]);
        }
      u16 ov[8];
#pragma unroll
      for (int j = 0; j < 8; ++j) {
        const float g = 0.5f * a[j] * (1.0f + erff(a[j] * 0.70710678118654752f));
        ov[j] = inb ? f2bf(g) : (u16)0;
      }
      *reinterpret_cast<uint4*>(Bbuf + px * 32 + o * 8) = pack8(ov);
    }
  }
  __syncthreads();

  // P2: out = x + dw2(s1)+b2 over 16x8 (always inside image)
  {
    float w[72], bi[8];
#pragma unroll
    for (int j = 0; j < 8; ++j) {
#pragma unroll
      for (int k = 0; k < 9; ++k) w[j * 9 + k] = w2g[(c0 + j) * 9 + k];
      bi[j] = b2g[c0 + j];
    }
    for (int i = t; i < 128 * 4; i += 256) {
      const int px = i >> 2;
      const int sx = px & 15, sy = px >> 4;
      float a[8];
#pragma unroll
      for (int j = 0; j < 8; ++j) a[j] = bi[j];
#pragma unroll
      for (int ky = 0; ky < 3; ++ky)
#pragma unroll
        for (int kx = 0; kx < 3; ++kx) {
          float f[8];
          unpack8(*reinterpret_cast<const uint4*>(
                      Bbuf + ((sy + ky) * 18 + sx + kx) * 32 + o * 8), f);
#pragma unroll
          for (int j = 0; j < 8; ++j) a[j] = fmaf(w[j * 9 + ky * 3 + kx], f[j], a[j]);
        }
      float xr[8];
      unpack8(*reinterpret_cast<const uint4*>(
                  Abuf + ((sy + 2) * 20 + sx + 2) * 32 + o * 8), xr);
      u16 ov[8];
#pragma unroll
      for (int j = 0; j < 8; ++j) ov[j] = f2bf(a[j] + xr[j]);
      u16* dst = x2 + ((size_t)((b << 16) + ((y0 + sy) << 8) + x0 + sx)) * 256 + cg * 32 + o * 8;
      *reinterpret_cast<uint4*>(dst) = pack8(ov);
    }
  }
}

// ---------------------------------------------------------------------------
// chain3: three chained per-head dw3x3, tile 16x8. RED: 1=sumsq, 2=sum.
// input region 22x14 (off -3, A), s1 20x12 (off -2, B), s2 18x10 (off -1,
// aliases A), out 16x8. Intermediates forced to 0 outside image.
// grid (16, 32, 16): (tx, ty, b*8+h)
template <int RED>
__global__ __launch_bounds__(256) void chain3_kernel(
    const u16* __restrict__ in, u16* __restrict__ out,
    const float* __restrict__ w1g, const float* __restrict__ w2g,
    const float* __restrict__ w3g, float* __restrict__ red) {
  const int t = threadIdx.x;
  const int o = t & 3;
  const int bz = blockIdx.z;
  const int h = bz & 7;
  const int b = bz >> 3;
  const int x0 = blockIdx.x * 16;
  const int y0 = blockIdx.y * 8;

  __shared__ __align__(16) u16 Abuf[308 * 32];  // input 22x14 / later s2 18x10
  __shared__ __align__(16) u16 Bbuf[240 * 32];  // s1 20x12
  __shared__ float rbuf[32];
  if (t < 32) rbuf[t] = 0.f;

  float w1[9], w2[9], w3[9];
#pragma unroll
  for (int k = 0; k < 9; ++k) {
    w1[k] = w1g[h * 9 + k];
    w2[k] = w2g[h * 9 + k];
    w3[k] = w3g[h * 9 + k];
  }

  // P0: load input region
  for (int i = t; i < 308 * 4; i += 256) {
    const int px = i >> 2, oo = i & 3;
    const int lx = px % 22, ly = px / 22;
    const int gx = x0 - 3 + lx, gy = y0 - 3 + ly;
    uint4 v = {0, 0, 0, 0};
    if (gx >= 0 && gx < 256 && gy >= 0 && gy < 256)
      v = *reinterpret_cast<const uint4*>(
          in + ((size_t)((b << 16) + (gy << 8) + gx)) * 256 + h * 32 + oo * 8);
    *reinterpret_cast<uint4*>(Abuf + px * 32 + oo * 8) = v;
  }
  __syncthreads();

  // P1: s1 over 20x12 — zero outside image
  for (int i = t; i < 240 * 4; i += 256) {
    const int px = i >> 2;
    const int sx = px % 20, sy = px / 20;
    const int gx = x0 - 2 + sx, gy = y0 - 2 + sy;
    const bool inb = (gx >= 0 && gx < 256 && gy >= 0 && gy < 256);
    float a[8] = {0, 0, 0, 0, 0, 0, 0, 0};
#pragma unroll
    for (int ky = 0; ky < 3; ++ky)
#pragma unroll
      for (int kx = 0; kx < 3; ++kx) {
        float f[8];
        unpack8(*reinterpret_cast<const uint4*>(
                    Abuf + ((sy + ky) * 22 + sx + kx) * 32 + o * 8), f);
#pragma unroll
        for (int j = 0; j < 8; ++j) a[j] = fmaf(w1[ky * 3 + kx], f[j], a[j]);
      }
    u16 ov[8];
#pragma unroll
    for (int j = 0; j < 8; ++j) ov[j] = inb ? f2bf(a[j]) : (u16)0;
    *reinterpret_cast<uint4*>(Bbuf + px * 32 + o * 8) = pack8(ov);
  }
  __syncthreads();

  // P2: s2 over 18x10 -> C (aliases Abuf) — zero outside image
  for (int i = t; i < 180 * 4; i += 256) {
    const int px = i >> 2;
    const int sx = px % 18, sy = px / 18;
    const int gx = x0 - 1 + sx, gy = y0 - 1 + sy;
    const bool inb = (gx >= 0 && gx < 256 && gy >= 0 && gy < 256);
    float a[8] = {0, 0, 0, 0, 0, 0, 0, 0};
#pragma unroll
    for (int ky = 0; ky < 3; ++ky)
#pragma unroll
      for (int kx = 0; kx < 3; ++kx) {
        float f[8];
        unpack8(*reinterpret_cast<const uint4*>(
                    Bbuf + ((sy + ky) * 20 + sx + kx) * 32 + o * 8), f);
#pragma unroll
        for (int j = 0; j < 8; ++j) a[j] = fmaf(w2[ky * 3 + kx], f[j], a[j]);
      }
    u16 ov[8];
#pragma unroll
    for (int j = 0; j < 8; ++j) ov[j] = inb ? f2bf(a[j]) : (u16)0;
    *reinterpret_cast<uint4*>(Abuf + px * 32 + o * 8) = pack8(ov);
  }
  __syncthreads();

  // P3: out over 16x8
  float racc[8] = {0, 0, 0, 0, 0, 0, 0, 0};
  for (int i = t; i < 128 * 4; i += 256) {
    const int px = i >> 2;
    const int sx = px & 15, sy = px >> 4;
    float a[8] = {0, 0, 0, 0, 0, 0, 0, 0};
#pragma unroll
    for (int ky = 0; ky < 3; ++ky)
#pragma unroll
      for (int kx = 0; kx < 3; ++kx) {
        float f[8];
        unpack8(*reinterpret_cast<const uint4*>(
                    Abuf + ((sy + ky) * 18 + sx + kx) * 32 + o * 8), f);
#pragma unroll
        for (int j = 0; j < 8; ++j) a[j] = fmaf(w3[ky * 3 + kx], f[j], a[j]);
      }
    u16 ov[8];
#pragma unroll
    for (int j = 0; j < 8; ++j) {
      ov[j] = f2bf(a[j]);
      const float rv = bf2f(ov[j]);
      if (RED == 1) racc[j] = fmaf(rv, rv, racc[j]);
      if (RED == 2) racc[j] += rv;
    }
    u16* dst = out + ((size_t)((b << 16) + ((y0 + sy) << 8) + x0 + sx)) * 256 + h * 32 + o * 8;
    *reinterpret_cast<uint4*>(dst) = pack8(ov);
  }
  __syncthreads();
#pragma unroll
  for (int j = 0; j < 8; ++j) atomicAdd(&rbuf[o * 8 + j], racc[j]);
  __syncthreads();
  if (t < 32) atomicAdd(&red[b * 256 + h * 32 + t], rbuf[t]);
}

// ---------------------------------------------------------------------------
// kchain_gram: k chain fused with Gram vs q3 tile. k3 never leaves HBM.
// G[d][e] += sum_px k3[d,px] q3[e,px]; also sqk (sum of k3^2).
// grid (16, 32, 16): (tx, ty, b*8+h). Tile 16x8 = 128 px, K=128 MFMA.
__global__ __launch_bounds__(256) void kchain_gram_kernel(
    const u16* __restrict__ in, const u16* __restrict__ q3,
    const float* __restrict__ w1g, const float* __restrict__ w2g,
    const float* __restrict__ w3g, float* __restrict__ G, float* __restrict__ sqk) {
  const int t = threadIdx.x;
  const int o = t & 3;
  const int bz = blockIdx.z;
  const int h = bz & 7;
  const int b = bz >> 3;
  const int x0 = blockIdx.x * 16;
  const int y0 = blockIdx.y * 8;

  __shared__ __align__(16) u16 Abuf[308 * 32];
  __shared__ __align__(16) u16 Bbuf[240 * 32];
  __shared__ __align__(16) u16 K3s[32 * 132];  // [d][px], pad 4
  __shared__ __align__(16) u16 Q3s[32 * 132];  // [e][px]
  __shared__ float rbuf[32];
  if (t < 32) rbuf[t] = 0.f;

  float w1[9], w2[9], w3[9];
#pragma unroll
  for (int k = 0; k < 9; ++k) {
    w1[k] = w1g[h * 9 + k];
    w2[k] = w2g[h * 9 + k];
    w3[k] = w3g[h * 9 + k];
  }

  for (int i = t; i < 308 * 4; i += 256) {
    const int px = i >> 2, oo = i & 3;
    const int lx = px % 22, ly = px / 22;
    const int gx = x0 - 3 + lx, gy = y0 - 3 + ly;
    uint4 v = {0, 0, 0, 0};
    if (gx >= 0 && gx < 256 && gy >= 0 && gy < 256)
      v = *reinterpret_cast<const uint4*>(
          in + ((size_t)((b << 16) + (gy << 8) + gx)) * 256 + h * 32 + oo * 8);
    *reinterpret_cast<uint4*>(Abuf + px * 32 + oo * 8) = v;
  }
  __syncthreads();

  for (int i = t; i < 240 * 4; i += 256) {
    const int px = i >> 2;
    const int sx = px % 20, sy = px / 20;
    const int gx = x0 - 2 + sx, gy = y0 - 2 + sy;
    const bool inb = (gx >= 0 && gx < 256 && gy >= 0 && gy < 256);
    float a[8] = {0, 0, 0, 0, 0, 0, 0, 0};
#pragma unroll
    for (int ky = 0; ky < 3; ++ky)
#pragma unroll
      for (int kx = 0; kx < 3; ++kx) {
        float f[8];
        unpack8(*reinterpret_cast<const uint4*>(
                    Abuf + ((sy + ky) * 22 + sx + kx) * 32 + o * 8), f);
#pragma unroll
        for (int j = 0; j < 8; ++j) a[j] = fmaf(w1[ky * 3 + kx], f[j], a[j]);
      }
    u16 ov[8];
#pragma unroll
    for (int j = 0; j < 8; ++j) ov[j] = inb ? f2bf(a[j]) : (u16)0;
    *reinterpret_cast<uint4*>(Bbuf + px * 32 + o * 8) = pack8(ov);
  }
  __syncthreads();

  for (int i = t; i < 180 * 4; i += 256) {
    const int px = i >> 2;
    const int sx = px % 18, sy = px / 18;
    const int gx = x0 - 1 + sx, gy = y0 - 1 + sy;
    const bool inb = (gx >= 0 && gx < 256 && gy >= 0 && gy < 256);
    float a[8] = {0, 0, 0, 0, 0, 0, 0, 0};
#pragma unroll
    for (int ky = 0; ky < 3; ++ky)
#pragma unroll
      for (int kx = 0; kx < 3; ++kx) {
        float f[8];
        unpack8(*reinterpret_cast<const uint4*>(
                    Bbuf + ((sy + ky) * 20 + sx + kx) * 32 + o * 8), f);
#pragma unroll
        for (int j = 0; j < 8; ++j) a[j] = fmaf(w2[ky * 3 + kx], f[j], a[j]);
      }
    u16 ov[8];
#pragma unroll
    for (int j = 0; j < 8; ++j) ov[j] = inb ? f2bf(a[j]) : (u16)0;
    *reinterpret_cast<uint4*>(Abuf + px * 32 + o * 8) = pack8(ov);
  }
  __syncthreads();

  // P3: k3 tile -> K3s (transposed [d][px]) + sqk accum; q3 tile -> Q3s
  float racc[8] = {0, 0, 0, 0, 0, 0, 0, 0};
  for (int i = t; i < 128 * 4; i += 256) {
    const int px = i >> 2;
    const int sx = px & 15, sy = px >> 4;
    float a[8] = {0, 0, 0, 0, 0, 0, 0, 0};
#pragma unroll
    for (int ky = 0; ky < 3; ++ky)
#pragma unroll
      for (int kx = 0; kx < 3; ++kx) {
        float f[8];
        unpack8(*reinterpret_cast<const uint4*>(
                    Abuf + ((sy + ky) * 18 + sx + kx) * 32 + o * 8), f);
#pragma unroll
        for (int j = 0; j < 8; ++j) a[j] = fmaf(w3[ky * 3 + kx], f[j], a[j]);
      }
#pragma unroll
    for (int j = 0; j < 8; ++j) {
      const u16 kb16 = f2bf(a[j]);
      const float kv = bf2f(kb16);
      K3s[(o * 8 + j) * 132 + px] = kb16;
      racc[j] = fmaf(kv, kv, racc[j]);
    }
    const uint4 uq = *reinterpret_cast<const uint4*>(
        q3 + ((size_t)((b << 16) + ((y0 + sy) << 8) + x0 + sx)) * 256 + h * 32 + o * 8);
    Q3s[(o * 8 + 0) * 132 + px] = (u16)(uq.x & 0xffffu);
    Q3s[(o * 8 + 1) * 132 + px] = (u16)(uq.x >> 16);
    Q3s[(o * 8 + 2) * 132 + px] = (u16)(uq.y & 0xffffu);
    Q3s[(o * 8 + 3) * 132 + px] = (u16)(uq.y >> 16);
    Q3s[(o * 8 + 4) * 132 + px] = (u16)(uq.z & 0xffffu);
    Q3s[(o * 8 + 5) * 132 + px] = (u16)(uq.z >> 16);
    Q3s[(o * 8 + 6) * 132 + px] = (u16)(uq.w & 0xffffu);
    Q3s[(o * 8 + 7) * 132 + px] = (u16)(uq.w >> 16);
  }
  __syncthreads();
#pragma unroll
  for (int j = 0; j < 8; ++j) atomicAdd(&rbuf[o * 8 + j], racc[j]);
  __syncthreads();
  if (t < 32) atomicAdd(&sqk[b * 256 + h * 32 + t], rbuf[t]);

  // Gram MFMA: wave -> 16x16 quadrant, K=128
  const int wave = t >> 6;
  const int lane = t & 63;
  const int quad = lane >> 4;
  const int l15 = lane & 15;
  const int d0 = (wave & 1) * 16;
  const int e0 = (wave >> 1) * 16;
  f32x4_t acc = {0.f, 0.f, 0.f, 0.f};
#pragma unroll
  for (int kb = 0; kb < 4; ++kb) {
    const bf16x8_t av = *reinterpret_cast<const bf16x8_t*>(
        &K3s[(d0 + l15) * 132 + kb * 32 + quad * 8]);
    const bf16x8_t bv = *reinterpret_cast<const bf16x8_t*>(
        &Q3s[(e0 + l15) * 132 + kb * 32 + quad * 8]);
    acc = __builtin_amdgcn_mfma_f32_16x16x32_bf16(av, bv, acc, 0, 0, 0);
  }
  float* Gp = G + (size_t)((b * 8 + h) * 32) * 32;
#pragma unroll
  for (int r = 0; r < 4; ++r)
    atomicAdd(&Gp[(d0 + quad * 4 + r) * 32 + e0 + l15], acc[r]);
}

// ---------------------------------------------------------------------------
// attn finalize: normalize Gram, conv1d diag, softmax.
__global__ __launch_bounds__(256) void attn_kernel(
    const float* __restrict__ G, const float* __restrict__ sqq,
    const float* __restrict__ sqk, const float* __restrict__ vsum,
    const float* __restrict__ cw, const float* __restrict__ cb,
    const float* __restrict__ rs1, const float* __restrict__ rs2,
    float* __restrict__ attn) {
  const int b = blockIdx.x;
  const int t = threadIdx.x;
  const int h = t >> 5;
  const int d = t & 31;
  __shared__ float vm[8][34];
  __shared__ float nq[256];
  vm[h][d + 1] = vsum[b * 256 + t] * (1.0f / 65536.0f);
  if (t < 8) { vm[t][0] = 0.f; vm[t][33] = 0.f; }
  nq[t] = fmaxf(sqrtf(sqq[b * 256 + t]), 1e-12f);
  __syncthreads();

  float av = cb[h];
#pragma unroll
  for (int i = 0; i < 8; ++i)
#pragma unroll
    for (int tau = 0; tau < 3; ++tau)
      av = fmaf(cw[h * 24 + i * 3 + tau], vm[i][d + tau], av);

  const float nk = fmaxf(sqrtf(sqk[b * 256 + t]), 1e-12f);
  const float rsc = rs1[h];
  const float rsc2 = rs2[h];
  const float* Gp = G + (size_t)((b * 8 + h) * 32 + d) * 32;
  float L[32];
#pragma unroll
  for (int e = 0; e < 32; ++e) {
    float l = Gp[e] * rsc / (nk * nq[h * 32 + e]);
    if (e == d) l += av * rsc2;
    L[e] = l;
  }
  float mx = L[0];
#pragma unroll
  for (int e = 1; e < 32; ++e) mx = fmaxf(mx, L[e]);
  float s = 0.f;
#pragma unroll
  for (int e = 0; e < 32; ++e) {
    L[e] = expf(L[e] - mx);
    s += L[e];
  }
  const float inv = 1.0f / s;
  float* Ap = attn + (size_t)((b * 8 + h) * 32 + d) * 32;
#pragma unroll
  for (int e = 0; e < 32; ++e) Ap[e] = L[e] * inv;
}

// M_b[c'][h*32+e] = sum_d proj_w[c'][h*32+d] * attn[b,h,d,e]  (bf16)
__global__ __launch_bounds__(256) void mbuild_kernel(
    const float* __restrict__ attn, const float* __restrict__ pw,
    u16* __restrict__ M) {
  const int bid = blockIdx.x;
  const int b = bid >> 3;
  const int h = bid & 7;
  const int t = threadIdx.x;
  __shared__ float at[32][33];
#pragma unroll
  for (int i = 0; i < 4; ++i) {
    const int idx = t * 4 + i;
    at[idx >> 5][idx & 31] = attn[(size_t)(b * 8 + h) * 1024 + idx];
  }
  __syncthreads();
  float pwf[32];
#pragma unroll
  for (int dd = 0; dd < 32; ++dd) pwf[dd] = pw[(size_t)t * 256 + h * 32 + dd];
  u16* Mp = M + (size_t)b * 65536 + (size_t)t * 256 + h * 32;
#pragma unroll
  for (int e = 0; e < 32; ++e) {
    float s = 0.f;
#pragma unroll
    for (int dd = 0; dd < 32; ++dd) s = fmaf(pwf[dd], at[dd][e], s);
    Mp[e] = f2bf(s);
  }
}

// out[m][c'] = sum_k v3[m][k] * M_b[c'][k] + proj_b[c'].  128x64 tile, fp32 out.
__global__ __launch_bounds__(256) void gemm_kernel(
    const u16* __restrict__ V, const u16* __restrict__ Mm,
    const float* __restrict__ pb, float* __restrict__ out) {
  const int m0 = blockIdx.x * 128;
  const int n0 = blockIdx.y * 64;
  const int b = m0 >> 16;
  const u16* Mb = Mm + (size_t)b * 65536;

  __shared__ __align__(16) u16 As[128][72];
  __shared__ __align__(16) u16 Bs[64][72];

  const int t = threadIdx.x;
  const int wave = t >> 6;
  const int lane = t & 63;
  const int quad = lane >> 4;
  const int l15 = lane & 15;

  f32x4_t acc[2][4];
#pragma unroll
  for (int mt = 0; mt < 2; ++mt)
#pragma unroll
    for (int nt = 0; nt < 4; ++nt) acc[mt][nt] = {0.f, 0.f, 0.f, 0.f};

  for (int k0 = 0; k0 < 256; k0 += 64) {
#pragma unroll
    for (int i = 0; i < 4; ++i) {
      const int id = t + 256 * i;
      const int row = id >> 3;
      const int c8 = id & 7;
      *reinterpret_cast<uint4*>(&As[row][c8 * 8]) = *reinterpret_cast<const uint4*>(
          &V[(size_t)(m0 + row) * 256 + k0 + c8 * 8]);
    }
#pragma unroll
    for (int i = 0; i < 2; ++i) {
      const int id = t + 256 * i;
      const int row = id >> 3;
      const int c8 = id & 7;
      *reinterpret_cast<uint4*>(&Bs[row][c8 * 8]) = *reinterpret_cast<const uint4*>(
          &Mb[(size_t)(n0 + row) * 256 + k0 + c8 * 8]);
    }
    __syncthreads();
#pragma unroll
    for (int ks = 0; ks < 2; ++ks) {
      bf16x8_t af[2], bfv[4];
#pragma unroll
      for (int mt = 0; mt < 2; ++mt)
        af[mt] = *reinterpret_cast<const bf16x8_t*>(
            &As[wave * 32 + mt * 16 + l15][ks * 32 + quad * 8]);
#pragma unroll
      for (int nt = 0; nt < 4; ++nt)
        bfv[nt] = *reinterpret_cast<const bf16x8_t*>(
            &Bs[nt * 16 + l15][ks * 32 + quad * 8]);
#pragma unroll
      for (int mt = 0; mt < 2; ++mt)
#pragma unroll
        for (int nt = 0; nt < 4; ++nt)
          acc[mt][nt] =
              __builtin_amdgcn_mfma_f32_16x16x32_bf16(af[mt], bfv[nt], acc[mt][nt], 0, 0, 0);
    }
    __syncthreads();
  }

#pragma unroll
  for (int nt = 0; nt < 4; ++nt) {
    const int col = n0 + nt * 16 + l15;
    const float pbf = pb[col];
#pragma unroll
    for (int mt = 0; mt < 2; ++mt) {
#pragma unroll
      for (int r = 0; r < 4; ++r) {
        const int m = m0 + wave * 32 + mt * 16 + quad * 4 + r;
        out[(size_t)m * 256 + col] = acc[mt][nt][r] + pbf;
      }
    }
  }
}

extern "C" void kernel_launch(void* const* d_in, const int* in_sizes, int n_in,
                              void* d_out, int out_size, void* d_ws, size_t ws_size,
                              hipStream_t stream) {
  const float* x_in = (const float*)d_in[0];
  const float* qw1 = (const float*)d_in[1];
  const float* qw2 = (const float*)d_in[2];
  const float* qw3 = (const float*)d_in[3];
  const float* kw1 = (const float*)d_in[4];
  const float* kw2 = (const float*)d_in[5];
  const float* kw3 = (const float*)d_in[6];
  const float* vw1 = (const float*)d_in[7];
  const float* vw2 = (const float*)d_in[8];
  const float* vw3 = (const float*)d_in[9];
  const float* posw1 = (const float*)d_in[10];
  const float* posb1 = (const float*)d_in[11];
  const float* posw2 = (const float*)d_in[12];
  const float* posb2 = (const float*)d_in[13];
  const float* cw = (const float*)d_in[14];
  const float* cb = (const float*)d_in[15];
  const float* rs1 = (const float*)d_in[16];
  const float* rs2 = (const float*)d_in[17];
  const float* pw = (const float*)d_in[18];
  const float* pb = (const float*)d_in[19];

  char* ws = (char*)d_ws;
  const size_t SLOT = 67108864;  // one (2,256,256,256) bf16 image
  u16* S0 = (u16*)(ws);            // x2
  u16* S1 = (u16*)(ws + SLOT);     // v3
  u16* D0 = (u16*)d_out;           // q3 (dead before gemm overwrites d_out)
  char* SM = ws + 2 * SLOT;
  float* G = (float*)(SM);              // 2*8*32*32 f32
  float* sqq = (float*)(SM + 65536);
  float* sqk = (float*)(SM + 67584);
  float* vsum = (float*)(SM + 69632);
  float* attn = (float*)(SM + 71680);
  u16* Mm = (u16*)(SM + 137216);

  hipMemsetAsync(SM, 0, 71680, stream);

  const dim3 tgrid(16, 32, 16);
  posemb_kernel<<<tgrid, 256, 0, stream>>>(x_in, S0, posw1, posb1, posw2, posb2);
  chain3_kernel<1><<<tgrid, 256, 0, stream>>>(S0, D0, qw1, qw2, qw3, sqq);
  kchain_gram_kernel<<<tgrid, 256, 0, stream>>>(S0, D0, kw1, kw2, kw3, G, sqk);
  chain3_kernel<2><<<tgrid, 256, 0, stream>>>(S0, S1, vw1, vw2, vw3, vsum);
  attn_kernel<<<2, 256, 0, stream>>>(G, sqq, sqk, vsum, cw, cb, rs1, rs2, attn);
  mbuild_kernel<<<16, 256, 0, stream>>>(attn, pw, Mm);
  gemm_kernel<<<dim3(1024, 4), 256, 0, stream>>>(S1, Mm, pb, (float*)d_out);
}